// Round 10
// baseline (313.387 us; speedup 1.0000x reference)
//
#include <hip/hip_runtime.h>
#include <hip/hip_bf16.h>
#include <math.h>

#define N_NODES 8192
#define IN_DIM  512
#define H_DIM   128
#define KC      1024              // K-chunk per k-block in k_A (bitmask path)
#define NKB     (N_NODES / KC)    // 8
#define BMR     64                // adj rows per k_A block (4 waves x 16)
#define NTW     (N_NODES / 64)    // bitmask u64 words per row (128)

typedef __attribute__((ext_vector_type(8))) short bf16x8;
typedef __attribute__((ext_vector_type(4))) float f32x4;

__device__ __forceinline__ float lrelu(float x) { return fmaxf(x, 0.2f * x); }

__device__ __forceinline__ unsigned int f2mono(float x) {
    unsigned int b = __float_as_uint(x);
    return (b & 0x80000000u) ? ~b : (b | 0x80000000u);
}
__device__ __forceinline__ float mono2f(unsigned int u) {
    unsigned int b = (u & 0x80000000u) ? (u ^ 0x80000000u) : ~u;
    return __uint_as_float(b);
}

__device__ __forceinline__ short f2bf(float x) {
    union { __hip_bfloat16 h; short s; } cv;
    cv.h = __float2bfloat16(x);
    return cv.s;
}

// Wh = h @ W_w^T + W_b (f32) ; also WhT = bf16 transpose [H_DIM][N_NODES]
__global__ __launch_bounds__(256) void k_wh(const float* __restrict__ h,
                                            const float* __restrict__ Ww,
                                            const float* __restrict__ Wb,
                                            float* __restrict__ Wh,
                                            __hip_bfloat16* __restrict__ WhT) {
    const int BM = 32, BK = 64;
    __shared__ float hT[BK][BM + 4];
    __shared__ float wT[BK][H_DIM + 4];
    const int tid = threadIdx.x;
    const int w = tid >> 6, lane = tid & 63;
    const int trm = tid >> 5, tcm = tid & 31;
    const int row0 = blockIdx.x * BM;

    float acc[4][4] = {};
    for (int k0 = 0; k0 < IN_DIM; k0 += BK) {
        __syncthreads();
        #pragma unroll
        for (int p = 0; p < 8; ++p) {
            int r = 4 * p + w;
            hT[lane][r] = h[(size_t)(row0 + r) * IN_DIM + k0 + lane];
        }
        #pragma unroll
        for (int p = 0; p < 32; ++p) {
            int c = 4 * p + w;
            wT[lane][c] = Ww[(size_t)c * IN_DIM + k0 + lane];
        }
        __syncthreads();
        #pragma unroll 8
        for (int kk = 0; kk < BK; ++kk) {
            f32x4 a4 = *(const f32x4*)&hT[kk][4 * trm];
            f32x4 b4 = *(const f32x4*)&wT[kk][4 * tcm];
            #pragma unroll
            for (int i = 0; i < 4; ++i)
                #pragma unroll
                for (int j = 0; j < 4; ++j)
                    acc[i][j] = fmaf(a4[i], b4[j], acc[i][j]);
        }
    }
    f32x4 wb4 = *(const f32x4*)&Wb[4 * tcm];
    #pragma unroll
    for (int i = 0; i < 4; ++i) {
        int row = row0 + 4 * trm + i;
        f32x4 v;
        #pragma unroll
        for (int jj = 0; jj < 4; ++jj) v[jj] = acc[i][jj] + wb4[jj];
        *(f32x4*)&Wh[(size_t)row * H_DIM + 4 * tcm] = v;
        #pragma unroll
        for (int jj = 0; jj < 4; ++jj)
            WhT[(size_t)(4 * tcm + jj) * N_NODES + row] = __float2bfloat16(v[jj]);
    }
}

// s_i = Wh_i . a ; global max(s) via mapped atomicMax
__global__ __launch_bounds__(256) void k_s(const float* __restrict__ Wh,
                                           const float* __restrict__ a,
                                           float* __restrict__ s,
                                           unsigned int* __restrict__ smax) {
    const int w = threadIdx.x >> 6, lane = threadIdx.x & 63;
    const int row = blockIdx.x * 4 + w;
    float2 av = *(const float2*)&a[lane * 2];
    float2 wh = *(const float2*)&Wh[(size_t)row * H_DIM + lane * 2];
    float v = wh.x * av.x + wh.y * av.y;
    #pragma unroll
    for (int off = 32; off > 0; off >>= 1) v += __shfl_down(v, off);
    __shared__ float bmax[4];
    if (lane == 0) { s[row] = v; bmax[w] = v; }
    __syncthreads();
    if (threadIdx.x == 0) {
        float m = fmaxf(fmaxf(bmax[0], bmax[1]), fmaxf(bmax[2], bmax[3]));
        atomicMax(smax, f2mono(m));
    }
}

// Streaming compress: bmask[row] bit j = (adj[row][j] != 0). One wave per row,
// 1KB contiguous nontemporal reads per wave-instr; nibbles packed to u64 via
// 4x shfl_xor OR-reduce; lanes 0/16/32/48 write the 4 words. ~268MB read, 8MB
// written, no barriers, no reuse -> should stream near copy BW.
__global__ __launch_bounds__(256) void k_mask(const float* __restrict__ adj,
                                              unsigned long long* __restrict__ bm) {
    const int lane = threadIdx.x & 63;
    const int row  = blockIdx.x * 4 + (threadIdx.x >> 6);
    const float* arow = adj + (size_t)row * N_NODES;
    unsigned long long* mrow = bm + (size_t)row * NTW;
    #pragma unroll 4
    for (int c = 0; c < N_NODES / 256; ++c) {      // 32 chunks of 256 cols
        f32x4 a4 = __builtin_nontemporal_load((const f32x4*)(arow + c * 256 + lane * 4));
        unsigned long long v = 0ull;
        v |= (a4[0] != 0.f) ? 1ull : 0ull;
        v |= (a4[1] != 0.f) ? 2ull : 0ull;
        v |= (a4[2] != 0.f) ? 4ull : 0ull;
        v |= (a4[3] != 0.f) ? 8ull : 0ull;
        v <<= (4 * (lane & 15));
        v |= __shfl_xor(v, 1);
        v |= __shfl_xor(v, 2);
        v |= __shfl_xor(v, 4);
        v |= __shfl_xor(v, 8);
        if ((lane & 15) == 0)
            mrow[c * 4 + (lane >> 4)] = v;
    }
}

// MFMA pass driven by the 8MB bitmask instead of the 268MB adj: NO LDS, NO
// barriers, no vmcnt drains (round-9 post-mortem: the 2-barrier-per-tile
// staging structure was the floor, not VALU). Each wave owns 16 rows x all 128
// H cols; per 64 cols it reads one u64 mask word (same-address broadcast
// across kq lanes), computes exp once per (i,j), and runs 16 MFMAs.
__global__ __launch_bounds__(256) void k_A(const unsigned long long* __restrict__ bm,
                                           const __hip_bfloat16* __restrict__ WhT,
                                           const float* __restrict__ s,
                                           const unsigned int* __restrict__ smaxp,
                                           float* __restrict__ denom,
                                           float* __restrict__ y) {
    const int lane = threadIdx.x & 63;
    const int w    = threadIdx.x >> 6;   // wave = row-group of 16
    const int r16  = lane & 15;
    const int kq   = lane >> 4;          // k-quarter: k = kq*8 + e
    const int row0 = blockIdx.x * BMR;
    const int j0   = blockIdx.y * KC;
    const int rowA = row0 + w * 16 + r16;

    const float smax = mono2f(*smaxp);
    const float si = s[rowA];
    const float mi = lrelu(si + smax);

    f32x4 acc[8] = {{0.f,0.f,0.f,0.f},{0.f,0.f,0.f,0.f},{0.f,0.f,0.f,0.f},{0.f,0.f,0.f,0.f},
                    {0.f,0.f,0.f,0.f},{0.f,0.f,0.f,0.f},{0.f,0.f,0.f,0.f},{0.f,0.f,0.f,0.f}};
    float dsum = 0.f;

    const float* sp = s + j0 + kq * 8;
    const __hip_bfloat16* bp = WhT + (size_t)r16 * N_NODES + j0 + kq * 8;
    const unsigned long long* mrow = bm + (size_t)rowA * NTW + (j0 >> 6);

    for (int bs = 0; bs < KC / 64; ++bs) {         // 16 mask words
        unsigned long long m64 = mrow[bs];
        #pragma unroll
        for (int sub = 0; sub < 2; ++sub) {
            const int ts = bs * 2 + sub;           // 32-col step in [0, KC/32)
            unsigned int bits = (unsigned int)(m64 >> (sub * 32 + kq * 8)) & 0xffu;

            f32x4 sc0 = *(const f32x4*)(sp + ts * 32);
            f32x4 sc1 = *(const f32x4*)(sp + ts * 32 + 4);
            float sv[8] = {sc0[0], sc0[1], sc0[2], sc0[3], sc1[0], sc1[1], sc1[2], sc1[3]};
            bf16x8 afrag;
            #pragma unroll
            for (int e = 0; e < 8; ++e) {
                bool nb = (bits >> e) & 1u;
                float ex = nb ? __expf(lrelu(si + sv[e]) - mi) : 0.f;
                dsum += ex;
                afrag[e] = f2bf(ex);
            }
            #pragma unroll
            for (int half = 0; half < 2; ++half) {
                bf16x8 bc[4];
                #pragma unroll
                for (int f = 0; f < 4; ++f)
                    bc[f] = *(const bf16x8*)(bp + (size_t)ts * 32 +
                                             (size_t)(half * 4 + f) * 16 * N_NODES);
                #pragma unroll
                for (int f = 0; f < 4; ++f)
                    acc[half * 4 + f] =
                        __builtin_amdgcn_mfma_f32_16x16x32_bf16(afrag, bc[f], acc[half * 4 + f], 0, 0, 0);
            }
        }
    }

    // denom partial: reduce over kq lanes (same r16)
    {
        float v = dsum;
        v += __shfl_xor(v, 16);
        v += __shfl_xor(v, 32);
        if (lane < 16) atomicAdd(&denom[row0 + w * 16 + lane], v);
    }
    // y partial: D layout col = f*16 + (lane&15), row = (lane>>4)*4 + reg
    #pragma unroll
    for (int f = 0; f < 8; ++f)
        #pragma unroll
        for (int i = 0; i < 4; ++i) {
            int rr = row0 + w * 16 + kq * 4 + i;
            int cc = f * 16 + r16;
            atomicAdd(&y[(size_t)rr * H_DIM + cc], acc[f][i]);
        }
}

// Fallback (ws too small for bmask): round-9 staged kernel, adj-direct.
__global__ __launch_bounds__(256) void k_A_fb(const float* __restrict__ adj,
                                              const __hip_bfloat16* __restrict__ WhT,
                                              const float* __restrict__ s,
                                              const unsigned int* __restrict__ smaxp,
                                              float* __restrict__ denom,
                                              float* __restrict__ y) {
    __shared__ unsigned char msk[BMR * 64];
    const int tid  = threadIdx.x;
    const int lane = tid & 63;
    const int w    = tid >> 6;
    const int r16  = lane & 15;
    const int kq   = lane >> 4;
    const int row0 = blockIdx.x * BMR;
    const int j0base = blockIdx.y * KC;
    const int rowA = row0 + w * 16 + r16;

    const float smax = mono2f(*smaxp);
    const float si = s[rowA];
    const float mi = lrelu(si + smax);

    f32x4 acc[8] = {{0.f,0.f,0.f,0.f},{0.f,0.f,0.f,0.f},{0.f,0.f,0.f,0.f},{0.f,0.f,0.f,0.f},
                    {0.f,0.f,0.f,0.f},{0.f,0.f,0.f,0.f},{0.f,0.f,0.f,0.f},{0.f,0.f,0.f,0.f}};
    float dsum = 0.f;

    const float* sp = s + j0base + kq * 8;
    const __hip_bfloat16* bp = WhT + (size_t)r16 * N_NODES + j0base + kq * 8;

    int sRow[4], sCol[4];
    #pragma unroll
    for (int p = 0; p < 4; ++p) {
        int seg = p * 256 + tid;
        sRow[p] = seg >> 4;
        sCol[p] = (seg & 15) * 4;
    }
    const int NBIG = KC / 64;
    f32x4 areg[4];
    #pragma unroll
    for (int p = 0; p < 4; ++p)
        areg[p] = __builtin_nontemporal_load(
            (const f32x4*)(adj + (size_t)(row0 + sRow[p]) * N_NODES + j0base + sCol[p]));

    for (int bs = 0; bs < NBIG; ++bs) {
        __syncthreads();
        #pragma unroll
        for (int p = 0; p < 4; ++p) {
            f32x4 a4 = areg[p];
            unsigned int mwd = 0u;
            mwd |= (a4[0] != 0.f) ? 0x00000001u : 0u;
            mwd |= (a4[1] != 0.f) ? 0x00000100u : 0u;
            mwd |= (a4[2] != 0.f) ? 0x00010000u : 0u;
            mwd |= (a4[3] != 0.f) ? 0x01000000u : 0u;
            int r = sRow[p], c = sCol[p];
            int slot = (c >> 3) ^ (r & 7);
            *(unsigned int*)&msk[r * 64 + (slot << 3) + (c & 7)] = mwd;
        }
        __syncthreads();
        if (bs + 1 < NBIG) {
            const int j1 = j0base + (bs + 1) * 64;
            #pragma unroll
            for (int p = 0; p < 4; ++p)
                areg[p] = __builtin_nontemporal_load(
                    (const f32x4*)(adj + (size_t)(row0 + sRow[p]) * N_NODES + j1 + sCol[p]));
        }
        #pragma unroll
        for (int sub = 0; sub < 2; ++sub) {
            const int ts = bs * 2 + sub;
            const int rT = w * 16 + r16;
            const int slotR = (sub * 4 + kq) ^ (r16 & 7);
            unsigned long long m8 = *(const unsigned long long*)&msk[rT * 64 + (slotR << 3)];
            unsigned int bits = (unsigned int)((m8 * 0x0102040810204080ull) >> 56) & 0xffu;

            f32x4 sc0 = *(const f32x4*)(sp + ts * 32);
            f32x4 sc1 = *(const f32x4*)(sp + ts * 32 + 4);
            float sv[8] = {sc0[0], sc0[1], sc0[2], sc0[3], sc1[0], sc1[1], sc1[2], sc1[3]};
            bf16x8 afrag;
            #pragma unroll
            for (int e = 0; e < 8; ++e) {
                bool nb = (bits >> e) & 1u;
                float ex = nb ? __expf(lrelu(si + sv[e]) - mi) : 0.f;
                dsum += ex;
                afrag[e] = f2bf(ex);
            }
            #pragma unroll
            for (int half = 0; half < 2; ++half) {
                bf16x8 bc[4];
                #pragma unroll
                for (int f = 0; f < 4; ++f)
                    bc[f] = *(const bf16x8*)(bp + (size_t)ts * 32 +
                                             (size_t)(half * 4 + f) * 16 * N_NODES);
                #pragma unroll
                for (int f = 0; f < 4; ++f)
                    acc[half * 4 + f] =
                        __builtin_amdgcn_mfma_f32_16x16x32_bf16(afrag, bc[f], acc[half * 4 + f], 0, 0, 0);
            }
        }
    }
    {
        float v = dsum;
        v += __shfl_xor(v, 16);
        v += __shfl_xor(v, 32);
        if (lane < 16) atomicAdd(&denom[row0 + w * 16 + lane], v);
    }
    #pragma unroll
    for (int f = 0; f < 8; ++f)
        #pragma unroll
        for (int i = 0; i < 4; ++i) {
            int rr = row0 + w * 16 + kq * 4 + i;
            int cc = f * 16 + r16;
            atomicAdd(&y[(size_t)rr * H_DIM + cc], acc[f][i]);
        }
}

// alpha_ij = ex_ij / denom_i ; reads 8MB bitmask (or adj fallback), writes 268MB nt
__global__ __launch_bounds__(256) void k_B(const unsigned long long* __restrict__ bmask,
                                           const float* __restrict__ adj,
                                           const float* __restrict__ s,
                                           const float* __restrict__ denom,
                                           const unsigned int* __restrict__ smaxp,
                                           float* __restrict__ alpha,
                                           int use_mask) {
    const int NSTEP = N_NODES / 256;
    const int w = threadIdx.x >> 6, lane = threadIdx.x & 63;
    const int row = blockIdx.x * 4 + w;
    const float smax = mono2f(*smaxp);
    const float si = s[row];
    const float mi = lrelu(si + smax);
    const float d = denom[row];
    const float rd = d > 0.f ? 1.f / d : 0.f;
    float* arow = alpha + (size_t)row * N_NODES;
    if (use_mask) {
        const unsigned long long* mrow = bmask + (size_t)row * NTW;
        #pragma unroll 4
        for (int t = 0; t < NSTEP; ++t) {
            int col = t * 256 + lane * 4;
            unsigned long long mb = mrow[t * 4 + (lane >> 4)];
            int sh = (lane & 15) * 4;
            f32x4 sj = *(const f32x4*)&s[col];
            f32x4 o;
            o[0] = ((mb >> (sh + 0)) & 1ull) ? __expf(lrelu(si + sj[0]) - mi) * rd : 0.f;
            o[1] = ((mb >> (sh + 1)) & 1ull) ? __expf(lrelu(si + sj[1]) - mi) * rd : 0.f;
            o[2] = ((mb >> (sh + 2)) & 1ull) ? __expf(lrelu(si + sj[2]) - mi) * rd : 0.f;
            o[3] = ((mb >> (sh + 3)) & 1ull) ? __expf(lrelu(si + sj[3]) - mi) * rd : 0.f;
            __builtin_nontemporal_store(o, (f32x4*)&arow[col]);
        }
    } else {
        const float* adjrow = adj + (size_t)row * N_NODES;
        #pragma unroll 4
        for (int t = 0; t < NSTEP; ++t) {
            int col = t * 256 + lane * 4;
            f32x4 a4 = __builtin_nontemporal_load((const f32x4*)&adjrow[col]);
            f32x4 sj = *(const f32x4*)&s[col];
            f32x4 o;
            o[0] = (a4[0] != 0.f) ? __expf(lrelu(si + sj[0]) - mi) * rd : 0.f;
            o[1] = (a4[1] != 0.f) ? __expf(lrelu(si + sj[1]) - mi) * rd : 0.f;
            o[2] = (a4[2] != 0.f) ? __expf(lrelu(si + sj[2]) - mi) * rd : 0.f;
            o[3] = (a4[3] != 0.f) ? __expf(lrelu(si + sj[3]) - mi) * rd : 0.f;
            __builtin_nontemporal_store(o, (f32x4*)&arow[col]);
        }
    }
}

// z = sigmoid(y/denom)
__global__ __launch_bounds__(256) void k_z(const float* __restrict__ y,
                                           const float* __restrict__ denom,
                                           float* __restrict__ z) {
    int i = blockIdx.x * 256 + threadIdx.x;
    int row = i >> 7;
    float d = denom[row];
    float rd = d > 0.f ? 1.f / d : 0.f;
    float v = y[i] * rd;
    z[i] = 1.f / (1.f + __expf(-v));
}

extern "C" void kernel_launch(void* const* d_in, const int* in_sizes, int n_in,
                              void* d_out, int out_size, void* d_ws, size_t ws_size,
                              hipStream_t stream) {
    const float* h   = (const float*)d_in[0];
    const float* adj = (const float*)d_in[1];
    const float* Ww  = (const float*)d_in[2];
    const float* Wb  = (const float*)d_in[3];
    const float* a   = (const float*)d_in[4];

    float* z     = (float*)d_out;
    float* alpha = z + (size_t)N_NODES * H_DIM;

    char* ws = (char*)d_ws;
    float* y     = (float*)ws;  ws += sizeof(float) * (size_t)N_NODES * H_DIM;   // 4MB (zeroed)
    float* denom = (float*)ws;  ws += sizeof(float) * N_NODES;                   // 32KB (zeroed)
    unsigned int* smax = (unsigned int*)ws;  ws += 256;                          // (zeroed)
    size_t zero_bytes = (size_t)(ws - (char*)d_ws);
    float* Wh    = (float*)ws;  ws += sizeof(float) * (size_t)N_NODES * H_DIM;   // 4MB
    __hip_bfloat16* WhT = (__hip_bfloat16*)ws;
    ws += sizeof(__hip_bfloat16) * (size_t)N_NODES * H_DIM;                      // 2MB
    float* s     = (float*)ws;  ws += sizeof(float) * N_NODES;                   // 32KB
    unsigned long long* bmask = (unsigned long long*)ws;
    size_t base_need  = (size_t)(ws - (char*)d_ws);
    size_t mask_bytes = (size_t)N_NODES * NTW * sizeof(unsigned long long);      // 8MB
    int use_mask = (ws_size >= base_need + mask_bytes) ? 1 : 0;

    (void)hipMemsetAsync(d_ws, 0, zero_bytes, stream);
    if (use_mask)
        hipLaunchKernelGGL(k_mask, dim3(N_NODES / 4), dim3(256), 0, stream, adj, bmask);
    hipLaunchKernelGGL(k_wh, dim3(N_NODES / 32), dim3(256), 0, stream, h, Ww, Wb, Wh, WhT);
    hipLaunchKernelGGL(k_s,  dim3(N_NODES / 4),  dim3(256), 0, stream, Wh, a, s, smax);
    if (use_mask)
        hipLaunchKernelGGL(k_A, dim3(N_NODES / BMR, NKB), dim3(256), 0, stream,
                           bmask, WhT, s, smax, denom, y);
    else
        hipLaunchKernelGGL(k_A_fb, dim3(N_NODES / BMR, NKB), dim3(256), 0, stream,
                           adj, WhT, s, smax, denom, y);
    hipLaunchKernelGGL(k_B,  dim3(N_NODES / 4),  dim3(256), 0, stream,
                       bmask, adj, s, denom, smax, alpha, use_mask);
    hipLaunchKernelGGL(k_z,  dim3((N_NODES * H_DIM) / 256), dim3(256), 0, stream,
                       y, denom, z);
}